// Round 7
// baseline (1441.968 us; speedup 1.0000x reference)
//
#include <hip/hip_runtime.h>

// LSTM BS=512, T=2048, IN=64, HS=128.  Single fused persistent kernel.
// 256 blocks x 2 batch rows, 8 waves. Z = x@W + bias is produced in LDS,
// double-buffered per 32-step chunk; the GEMM for chunk c+1 is interleaved
// into chunk c's scan steps (one 16-row m-tile every 8 steps), so its
// x-load latency and MFMA time hide inside the scan's dependency bubbles.
// Scan step: 16 MFMA (K=128, U*h), in-register cell update via ds_swizzle.

#define T_STEPS 2048
#define IN_DIM 64
#define HS 128
#define NG 512
#define ROWS 2
#define NBLK 256
#define NTHR 512
#define HSTR 144
#define CH 32
#define NCH (T_STEPS / CH)

typedef float f32x4 __attribute__((ext_vector_type(4)));
typedef short s16x8 __attribute__((ext_vector_type(8)));

__device__ __forceinline__ unsigned short f2bf(float f) {
  unsigned u = __float_as_uint(f);
  return (unsigned short)((u + 0x7fffu + ((u >> 16) & 1u)) >> 16);  // RNE
}
__device__ __forceinline__ float bf2f(unsigned short s) {
  return __int_as_float(((int)s) << 16);
}
__device__ __forceinline__ float rcpf(float x) { return __builtin_amdgcn_rcpf(x); }
__device__ __forceinline__ float sigm(float x) { return rcpf(1.0f + __expf(-x)); }
__device__ __forceinline__ float tanhfast(float x) {
  return 1.0f - 2.0f * rcpf(__expf(2.0f * x) + 1.0f);  // exact at +-inf
}

__global__ __launch_bounds__(NTHR, 1)
void lstm_fused(const float* __restrict__ X, const float* __restrict__ W,
                const float* __restrict__ U, const float* __restrict__ B,
                const float* __restrict__ LW, const float* __restrict__ LB,
                float* __restrict__ OUT) {
  // Zc[buf] cell (tl, col): 8 shorts = [r0:n0..n3 | r1:n0..n3]
  __shared__ __align__(16) short Zc[2][CH * 128 * 8];  // 2 x 64 KB
  __shared__ __align__(16) short Hb[2][ROWS * HSTR];   // h double buffer
  __shared__ float Ys[256];
  __shared__ float Ps[8];

  const int tid  = threadIdx.x;
  const int lane = tid & 63;
  const int w    = tid >> 6;
  const int blk  = blockIdx.x;
  const int lrow = lane & 15;
  const int lg   = lane >> 4;
  const int col8 = (w * 16 + lrow) * 8;   // Zc column offset (shorts)

  // ---- persistent weight fragments: wave w owns col p = n*128 + 16w + lrow
  s16x8 bfrU[4][4];   // K=128 (U)
  s16x8 bfrW[4][2];   // K=64  (W)
  float biasg[4];
#pragma unroll
  for (int n = 0; n < 4; ++n) {
    const int p = n * HS + w * 16 + lrow;
#pragma unroll
    for (int kt = 0; kt < 4; ++kt)
#pragma unroll
      for (int j = 0; j < 8; ++j)
        bfrU[n][kt][j] = (short)f2bf(U[(kt * 32 + (lg << 3) + j) * NG + p]);
#pragma unroll
    for (int kt = 0; kt < 2; ++kt)
#pragma unroll
      for (int j = 0; j < 8; ++j)
        bfrW[n][kt][j] = (short)f2bf(W[(kt * 32 + (lg << 3) + j) * NG + p]);
    biasg[n] = B[p];
  }

  // ---- GEMM A-tile source: lane -> batch row (lrow&1), t-row (lrow>>1) ----
  const float* xbA = X + ((long)(blk * ROWS + (lrow & 1)) * T_STEPS + (lrow >> 1)) * IN_DIM + (lg << 3);

  // q regs: x for the NEXT m-tile to be produced (chunk 0, mt 0 initially)
  f32x4 q0 = *(const f32x4*)(xbA);
  f32x4 q1 = *(const f32x4*)(xbA + 4);
  f32x4 q2 = *(const f32x4*)(xbA + 32);
  f32x4 q3 = *(const f32x4*)(xbA + 36);

  // produce m-tile mt into Zc[nbuf]; advance q to x at element-offset noff
  auto gemm_mt = [&](int mt, int nbuf, long noff) {
    s16x8 a0, a1;
#pragma unroll
    for (int j = 0; j < 4; ++j) {
      a0[j] = (short)f2bf(q0[j]); a0[4 + j] = (short)f2bf(q1[j]);
      a1[j] = (short)f2bf(q2[j]); a1[4 + j] = (short)f2bf(q3[j]);
    }
    const float* pn = xbA + noff;            // issue next loads early
    const f32x4 t0 = *(const f32x4*)(pn);
    const f32x4 t1 = *(const f32x4*)(pn + 4);
    const f32x4 t2 = *(const f32x4*)(pn + 32);
    const f32x4 t3 = *(const f32x4*)(pn + 36);
    f32x4 ac[4];
#pragma unroll
    for (int n = 0; n < 4; ++n) {
      ac[n][0] = biasg[n]; ac[n][1] = biasg[n];
      ac[n][2] = biasg[n]; ac[n][3] = biasg[n];
    }
#pragma unroll
    for (int n = 0; n < 4; ++n)
      ac[n] = __builtin_amdgcn_mfma_f32_16x16x32_bf16(a0, bfrW[n][0], ac[n], 0, 0, 0);
#pragma unroll
    for (int n = 0; n < 4; ++n)
      ac[n] = __builtin_amdgcn_mfma_f32_16x16x32_bf16(a1, bfrW[n][1], ac[n], 0, 0, 0);
    // D row d=4lg+rr -> m-row 16mt+d -> (tl = 8mt+2lg+(rr>>1), r = rr&1)
    s16x8 z0, z1;
#pragma unroll
    for (int n = 0; n < 4; ++n) {
      z0[n] = (short)f2bf(ac[n][0]); z0[4 + n] = (short)f2bf(ac[n][1]);
      z1[n] = (short)f2bf(ac[n][2]); z1[4 + n] = (short)f2bf(ac[n][3]);
    }
    const int tl0 = mt * 8 + 2 * lg;
    *(s16x8*)&Zc[nbuf][tl0 * 1024 + col8]       = z0;
    *(s16x8*)&Zc[nbuf][(tl0 + 1) * 1024 + col8] = z1;
    q0 = t0; q1 = t1; q2 = t2; q3 = t3;
  };

  // ---- prologue: GEMM chunk 0 into Zc[0] ----
#pragma unroll
  for (int mt = 0; mt < 4; ++mt) {
    const long noff = (mt < 3) ? (long)(mt + 1) * 8 * IN_DIM
                               : (long)CH * IN_DIM;   // chunk 1, mt 0
    gemm_mt(mt, 0, noff);
  }

  s16x8 afr[4];
  const s16x8 zer = {0, 0, 0, 0, 0, 0, 0, 0};
#pragma unroll
  for (int kt = 0; kt < 4; ++kt) afr[kt] = zer;  // h(0) = 0

  float creg = 0.f, hreg = 0.f;

  __syncthreads();
  s16x8 zreg = *(const s16x8*)&Zc[0][col8];      // Z(t=0)

#pragma unroll 1
  for (int c = 0; c < NCH; ++c) {
    const int cur = c & 1;
#pragma unroll 1
    for (int tl = 0; tl < CH; ++tl) {
      const int t = c * CH + tl;

      f32x4 acc[4];
#pragma unroll
      for (int n = 0; n < 4; ++n) {
        acc[n][0] = bf2f((unsigned short)zreg[n]);
        acc[n][1] = bf2f((unsigned short)zreg[4 + n]);
        acc[n][2] = 0.f; acc[n][3] = 0.f;
      }
      // prefetch Z for the next step (wraps into the other buffer at tl=31;
      // its GEMM writes are already barrier-separated)
      {
        const int nb  = (tl == CH - 1) ? (cur ^ 1) : cur;
        const int ntl = (tl + 1) & (CH - 1);
        zreg = *(const s16x8*)&Zc[nb][ntl * 1024 + col8];
      }

      // kt-outer: 4 independent acc chains; n-order {0,2,1,3} (i,g retire 1st)
      __builtin_amdgcn_s_setprio(1);
#pragma unroll
      for (int kt = 0; kt < 4; ++kt) {
        acc[0] = __builtin_amdgcn_mfma_f32_16x16x32_bf16(afr[kt], bfrU[0][kt], acc[0], 0, 0, 0);
        acc[2] = __builtin_amdgcn_mfma_f32_16x16x32_bf16(afr[kt], bfrU[2][kt], acc[2], 0, 0, 0);
        acc[1] = __builtin_amdgcn_mfma_f32_16x16x32_bf16(afr[kt], bfrU[1][kt], acc[1], 0, 0, 0);
        acc[3] = __builtin_amdgcn_mfma_f32_16x16x32_bf16(afr[kt], bfrU[3][kt], acc[3], 0, 0, 0);
      }
      __builtin_amdgcn_s_setprio(0);

      // interleaved producer: one m-tile of chunk c+1 every 8 steps.
      // Independent of the scan accs -> fills the activation-chain bubble.
      if ((tl & 7) == 2 && c + 1 < NCH) {
        const int mt = tl >> 3;
        long noff;
        if (mt < 3) noff = (long)(c + 1) * CH * IN_DIM + (long)(mt + 1) * 8 * IN_DIM;
        else        noff = (long)((c + 2 < NCH) ? c + 2 : c + 1) * CH * IN_DIM;
        gemm_mt(mt, cur ^ 1, noff);
      }

      // i,g first (their accs finish first), f,o while i*g computes
      const float s0 = __int_as_float(
          __builtin_amdgcn_ds_swizzle(__float_as_int(acc[0][1]), 0x401F));
      const float s2 = __int_as_float(
          __builtin_amdgcn_ds_swizzle(__float_as_int(acc[2][1]), 0x401F));
      const float v0 = (lane & 16) ? s0 : acc[0][0];
      const float v2 = (lane & 16) ? s2 : acc[2][0];
      const float iv = sigm(v0), gv = tanhfast(v2);
      const float pg = iv * gv;
      const float s1 = __int_as_float(
          __builtin_amdgcn_ds_swizzle(__float_as_int(acc[1][1]), 0x401F));
      const float s3 = __int_as_float(
          __builtin_amdgcn_ds_swizzle(__float_as_int(acc[3][1]), 0x401F));
      const float v1 = (lane & 16) ? s1 : acc[1][0];
      const float v3 = (lane & 16) ? s3 : acc[3][0];
      const float fv = sigm(v1), ov = sigm(v3);
      creg = fv * creg + pg;
      hreg = ov * tanhfast(creg);

      if (lane < 32) {
        const int col = w * 16 + lrow;
        const int r   = lg & 1;
        if (t < T_STEPS - 1) {
          Hb[(t + 1) & 1][r * HSTR + col] = (short)f2bf(hreg);
        } else {
          const int row = blk * ROWS + r;
          OUT[512 + row * HS + col]   = hreg;   // h_t
          OUT[66048 + row * HS + col] = creg;   // c_t
          Ys[r * HS + col] = LW[col] * hreg;    // y partials
        }
      }
      __syncthreads();

      if (t < T_STEPS - 1 && lrow < ROWS) {     // h fragments for step t+1
        const short* hb = &Hb[(t + 1) & 1][lrow * HSTR];
        afr[0] = *(const s16x8*)&hb[(lg << 3)];
        afr[1] = *(const s16x8*)&hb[32 + (lg << 3)];
        afr[2] = *(const s16x8*)&hb[64 + (lg << 3)];
        afr[3] = *(const s16x8*)&hb[96 + (lg << 3)];
      }
    }
  }

  // ---- y = h @ linear_w.T + b ----
  if (tid < 8) {
    const int r = tid >> 2, seg = tid & 3;
    float s = 0.f;
#pragma unroll 8
    for (int j = 0; j < 32; ++j) s += Ys[r * 128 + seg * 32 + j];
    Ps[tid] = s;
  }
  __syncthreads();
  if (tid < ROWS) {
    OUT[blk * ROWS + tid] = LB[0] + Ps[tid * 4] + Ps[tid * 4 + 1]
                                  + Ps[tid * 4 + 2] + Ps[tid * 4 + 3];
  }
}

extern "C" void kernel_launch(void* const* d_in, const int* in_sizes, int n_in,
                              void* d_out, int out_size, void* d_ws, size_t ws_size,
                              hipStream_t stream) {
  const float* X  = (const float*)d_in[0];
  const float* W  = (const float*)d_in[1];
  const float* U  = (const float*)d_in[2];
  const float* B  = (const float*)d_in[3];
  const float* LW = (const float*)d_in[4];
  const float* LB = (const float*)d_in[5];
  lstm_fused<<<dim3(NBLK), dim3(NTHR), 0, stream>>>(X, W, U, B, LW, LB, (float*)d_out);
}